// Round 1
// baseline (271.025 us; speedup 1.0000x reference)
//
#include <hip/hip_runtime.h>

// DeepFM fused ranker, fp32.
// Decomposition: 1 wave = 8 rows. Phase A gathers deep_in[200] to LDS and
// computes FM first/second order. Phase B/C do the MLP as register-blocked
// GEMVs: lane owns output neurons, 8 row-accumulators amortize each weight
// load; weights stream from global (L1/L2-resident), activations broadcast
// from LDS via ds_read_b128.

#define WAVES_PER_BLOCK 4
#define ROWS_PER_WAVE 8
#define ROWS_PER_BLOCK (WAVES_PER_BLOCK * ROWS_PER_WAVE)   // 32

__global__ __launch_bounds__(256) void deepfm_kernel(
    const int* __restrict__ user_id, const int* __restrict__ item_id,
    const int* __restrict__ gender_, const int* __restrict__ age_,
    const int* __restrict__ occ_, const int* __restrict__ genre_ids,
    const float* __restrict__ genre_mask, const float* __restrict__ dense,
    const float* __restrict__ fo_user, const float* __restrict__ fo_item,
    const float* __restrict__ fo_gender, const float* __restrict__ fo_age,
    const float* __restrict__ fo_occ, const float* __restrict__ fo_genre,
    const float* __restrict__ emb_user, const float* __restrict__ emb_item,
    const float* __restrict__ emb_gender, const float* __restrict__ emb_age,
    const float* __restrict__ emb_occ, const float* __restrict__ emb_genre,
    const float* __restrict__ dense_W, const float* __restrict__ dense_b,
    const float* __restrict__ W1, const float* __restrict__ b1,
    const float* __restrict__ W2, const float* __restrict__ b2,
    const float* __restrict__ Wout, const float* __restrict__ bout,
    float* __restrict__ out, int B)
{
    // per-wave region: 8 rows x 200 floats deep_in; h1 (8x128) overlays it later
    __shared__ float lds_di[WAVES_PER_BLOCK][ROWS_PER_WAVE][200];
    __shared__ float lds_rs[WAVES_PER_BLOCK][ROWS_PER_WAVE];  // first+second per row

    const int tid = threadIdx.x;
    const int wid = tid >> 6;
    const int lane = tid & 63;
    const int rowBase = blockIdx.x * ROWS_PER_BLOCK + wid * ROWS_PER_WAVE;

    // ---------------- Phase A: gather + FM first/second order ----------------
    for (int r = 0; r < ROWS_PER_WAVE; ++r) {
        const int row = rowBase + r;
        if (row >= B) break;  // wave-uniform

        const int uid = user_id[row], iid = item_id[row];
        const int g = gender_[row], a = age_[row], o = occ_[row];

        int gid[6]; float mk[6]; float msum = 0.f;
        #pragma unroll
        for (int t = 0; t < 6; ++t) {
            gid[t] = genre_ids[row * 6 + t];
            mk[t]  = genre_mask[row * 6 + t];
            msum  += mk[t];
        }
        const float inv_den = 1.0f / fmaxf(msum, 1.0f);

        // 6 fields x 32 dims gathered by 64 lanes in 3 steps.
        // lanes<32 handle fields 0,2,4 at dim=lane; lanes>=32 fields 1,3,5 at dim=lane-32
        float pe_sum = 0.f, pe_sq = 0.f;
        {
            float v = (lane < 32) ? emb_user[(size_t)uid * 32 + lane]
                                  : emb_item[(size_t)iid * 32 + (lane - 32)];
            lds_di[wid][r][lane] = v;
            pe_sum += v; pe_sq += v * v;
        }
        {
            float v = (lane < 32) ? emb_gender[g * 32 + lane]
                                  : emb_age[a * 32 + (lane - 32)];
            lds_di[wid][r][64 + lane] = v;
            pe_sum += v; pe_sq += v * v;
        }
        {
            float v;
            if (lane < 32) {
                v = emb_occ[o * 32 + lane];
            } else {
                const int d = lane - 32;
                float s = 0.f;
                #pragma unroll
                for (int t = 0; t < 6; ++t) s += mk[t] * emb_genre[gid[t] * 32 + d];
                v = s * inv_den;
            }
            lds_di[wid][r][128 + lane] = v;
            pe_sum += v; pe_sq += v * v;
        }
        if (lane < 8) lds_di[wid][r][192 + lane] = dense[(size_t)row * 8 + lane];

        // second order: combine even/odd field halves (dim d pairs lane d <-> d+32)
        float s2 = pe_sum + __shfl_xor(pe_sum, 32);
        float ss = pe_sq  + __shfl_xor(pe_sq, 32);
        float t2 = 0.5f * (s2 * s2 - ss);
        #pragma unroll
        for (int off = 16; off >= 1; off >>= 1) t2 += __shfl_xor(t2, off);  // sum over 32 dims

        // first order (redundant on all lanes; wave-uniform L1-broadcast loads)
        float fo = fo_user[uid] + fo_item[iid] + fo_gender[g] + fo_age[a] + fo_occ[o];
        float fg = 0.f;
        #pragma unroll
        for (int t = 0; t < 6; ++t) fg += mk[t] * fo_genre[gid[t]];
        fo += fg * inv_den;
        float dd = 0.f;
        #pragma unroll
        for (int j = 0; j < 8; ++j) dd += dense[(size_t)row * 8 + j] * dense_W[j];
        fo += dd + dense_b[0];

        if (lane == 0) lds_rs[wid][r] = fo + t2;
    }
    __syncthreads();

    // ---------------- Phase B: h1 = relu(deep_in @ W1^T + b1) ----------------
    // lane owns h1 neurons j0=lane, j1=lane+64; 8 row-accumulators each.
    float acc0[ROWS_PER_WAVE], acc1[ROWS_PER_WAVE];
    #pragma unroll
    for (int r = 0; r < ROWS_PER_WAVE; ++r) { acc0[r] = 0.f; acc1[r] = 0.f; }

    const float4* __restrict__ W1v = reinterpret_cast<const float4*>(W1);  // row stride 50 float4
    const float4* __restrict__ div_ = reinterpret_cast<const float4*>(&lds_di[wid][0][0]); // row stride 50

    for (int k4 = 0; k4 < 50; ++k4) {
        const float4 w0 = W1v[lane * 50 + k4];
        const float4 w1 = W1v[(lane + 64) * 50 + k4];
        #pragma unroll
        for (int r = 0; r < ROWS_PER_WAVE; ++r) {
            const float4 di = div_[r * 50 + k4];
            acc0[r] += w0.x * di.x + w0.y * di.y + w0.z * di.z + w0.w * di.w;
            acc1[r] += w1.x * di.x + w1.y * di.y + w1.z * di.z + w1.w * di.w;
        }
    }

    __syncthreads();  // wave's deep_in reads done; safe to overlay h1
    float* __restrict__ h1b = &lds_di[wid][0][0];  // h1[r][j] at r*128+j (8*128 <= 8*200)
    {
        const float bb0 = b1[lane], bb1 = b1[lane + 64];
        #pragma unroll
        for (int r = 0; r < ROWS_PER_WAVE; ++r) {
            h1b[r * 128 + lane]      = fmaxf(acc0[r] + bb0, 0.f);
            h1b[r * 128 + lane + 64] = fmaxf(acc1[r] + bb1, 0.f);
        }
    }
    __syncthreads();

    // ---------------- Phase C: h2 = relu(h1 @ W2^T + b2) ----------------
    float acc2[ROWS_PER_WAVE];
    #pragma unroll
    for (int r = 0; r < ROWS_PER_WAVE; ++r) acc2[r] = 0.f;

    const float4* __restrict__ W2v = reinterpret_cast<const float4*>(W2);  // row stride 32 float4
    const float4* __restrict__ h1v = reinterpret_cast<const float4*>(h1b); // row stride 32

    for (int k4 = 0; k4 < 32; ++k4) {
        const float4 w = W2v[lane * 32 + k4];
        #pragma unroll
        for (int r = 0; r < ROWS_PER_WAVE; ++r) {
            const float4 h = h1v[r * 32 + k4];
            acc2[r] += w.x * h.x + w.y * h.y + w.z * h.z + w.w * h.w;
        }
    }

    // ---------------- Phase D: out = Wout.h2 + bout + first + second ----------------
    const float wo = Wout[lane];
    const float bb2 = b2[lane];
    const float bo = bout[0];
    for (int r = 0; r < ROWS_PER_WAVE; ++r) {
        const int row = rowBase + r;
        const float h2 = fmaxf(acc2[r] + bb2, 0.f);
        float v = wo * h2;
        #pragma unroll
        for (int off = 32; off >= 1; off >>= 1) v += __shfl_xor(v, off);
        if (lane == 0 && row < B) out[row] = v + bo + lds_rs[wid][r];
    }
}

extern "C" void kernel_launch(void* const* d_in, const int* in_sizes, int n_in,
                              void* d_out, int out_size, void* d_ws, size_t ws_size,
                              hipStream_t stream) {
    const int B = in_sizes[0];
    const int grid = (B + ROWS_PER_BLOCK - 1) / ROWS_PER_BLOCK;  // 512 at B=16384
    deepfm_kernel<<<grid, 256, 0, stream>>>(
        (const int*)d_in[0],  (const int*)d_in[1],  (const int*)d_in[2],
        (const int*)d_in[3],  (const int*)d_in[4],  (const int*)d_in[5],
        (const float*)d_in[6],  (const float*)d_in[7],
        (const float*)d_in[8],  (const float*)d_in[9],  (const float*)d_in[10],
        (const float*)d_in[11], (const float*)d_in[12], (const float*)d_in[13],
        (const float*)d_in[14], (const float*)d_in[15], (const float*)d_in[16],
        (const float*)d_in[17], (const float*)d_in[18], (const float*)d_in[19],
        (const float*)d_in[20], (const float*)d_in[21],
        (const float*)d_in[22], (const float*)d_in[23],
        (const float*)d_in[24], (const float*)d_in[25],
        (const float*)d_in[26], (const float*)d_in[27],
        (float*)d_out, B);
}

// Round 2
// 266.144 us; speedup vs baseline: 1.0183x; 1.0183x over previous
//
#include <hip/hip_runtime.h>

// DeepFM fused ranker, fp32.
// R1: weight loads were fully uncoalesced (lane stride = W1 row = 800B).
// Fix: pack_weights pre-pass writes W1/W2 into lane-major packed layouts in
// d_ws so GEMV weight loads are single coalesced b128 per lane. Activations
// broadcast from LDS (uniform address = conflict-free). Phase A id loads
// hoisted + unrolled for gather ILP.

#define WAVES_PER_BLOCK 4
#define ROWS_PER_WAVE 8
#define ROWS_PER_BLOCK (WAVES_PER_BLOCK * ROWS_PER_WAVE)   // 32

// ---- pre-pass: pack W1 [128][200] -> W1p[k2][lane] float4 {j0k0,j1k0,j0k1,j1k1}
//                pack W2 [64][128]  -> W2p[k4][lane] float4 {4 k's for neuron lane}
__global__ void pack_weights(const float* __restrict__ W1, const float* __restrict__ W2,
                             float4* __restrict__ W1p, float4* __restrict__ W2p) {
    const int idx = blockIdx.x * blockDim.x + threadIdx.x;
    if (idx < 100 * 64) {
        const int k2 = idx >> 6, l = idx & 63;
        const int j0 = 2 * l, j1 = 2 * l + 1, k0 = 2 * k2, k1 = 2 * k2 + 1;
        W1p[idx] = make_float4(W1[j0 * 200 + k0], W1[j1 * 200 + k0],
                               W1[j0 * 200 + k1], W1[j1 * 200 + k1]);
    }
    if (idx < 32 * 64) {
        const int k4 = idx >> 6, l = idx & 63;
        const float* r = W2 + l * 128 + 4 * k4;
        W2p[idx] = make_float4(r[0], r[1], r[2], r[3]);
    }
}

__global__ __launch_bounds__(256) void deepfm_kernel(
    const int* __restrict__ user_id, const int* __restrict__ item_id,
    const int* __restrict__ gender_, const int* __restrict__ age_,
    const int* __restrict__ occ_, const int* __restrict__ genre_ids,
    const float* __restrict__ genre_mask, const float* __restrict__ dense,
    const float* __restrict__ fo_user, const float* __restrict__ fo_item,
    const float* __restrict__ fo_gender, const float* __restrict__ fo_age,
    const float* __restrict__ fo_occ, const float* __restrict__ fo_genre,
    const float* __restrict__ emb_user, const float* __restrict__ emb_item,
    const float* __restrict__ emb_gender, const float* __restrict__ emb_age,
    const float* __restrict__ emb_occ, const float* __restrict__ emb_genre,
    const float* __restrict__ dense_W, const float* __restrict__ dense_b,
    const float4* __restrict__ W1p, const float* __restrict__ b1,
    const float4* __restrict__ W2p, const float* __restrict__ b2,
    const float* __restrict__ Wout, const float* __restrict__ bout,
    float* __restrict__ out, int B)
{
    __shared__ float lds_di[WAVES_PER_BLOCK][ROWS_PER_WAVE][200];
    __shared__ float lds_rs[WAVES_PER_BLOCK][ROWS_PER_WAVE];

    const int tid = threadIdx.x;
    const int wid = tid >> 6;
    const int lane = tid & 63;
    const int rowBase = blockIdx.x * ROWS_PER_BLOCK + wid * ROWS_PER_WAVE;

    // ---------------- Phase A: gather + FM first/second order ----------------
    // hoist wave-uniform id loads for ILP across rows
    int uid[ROWS_PER_WAVE], iid[ROWS_PER_WAVE], gg[ROWS_PER_WAVE],
        aa[ROWS_PER_WAVE], oo[ROWS_PER_WAVE];
    #pragma unroll
    for (int r = 0; r < ROWS_PER_WAVE; ++r) {
        int row = rowBase + r; if (row >= B) row = B - 1;
        uid[r] = user_id[row]; iid[r] = item_id[row];
        gg[r] = gender_[row];  aa[r] = age_[row];  oo[r] = occ_[row];
    }

    #pragma unroll
    for (int r = 0; r < ROWS_PER_WAVE; ++r) {
        int row = rowBase + r; if (row >= B) row = B - 1;

        int gid[6]; float mk[6]; float msum = 0.f;
        #pragma unroll
        for (int t = 0; t < 6; ++t) {
            gid[t] = genre_ids[row * 6 + t];
            mk[t]  = genre_mask[row * 6 + t];
            msum  += mk[t];
        }
        const float inv_den = 1.0f / fmaxf(msum, 1.0f);

        float pe_sum = 0.f, pe_sq = 0.f;
        {
            float v = (lane < 32) ? emb_user[(size_t)uid[r] * 32 + lane]
                                  : emb_item[(size_t)iid[r] * 32 + (lane - 32)];
            lds_di[wid][r][lane] = v;
            pe_sum += v; pe_sq += v * v;
        }
        {
            float v = (lane < 32) ? emb_gender[gg[r] * 32 + lane]
                                  : emb_age[aa[r] * 32 + (lane - 32)];
            lds_di[wid][r][64 + lane] = v;
            pe_sum += v; pe_sq += v * v;
        }
        {
            float v;
            if (lane < 32) {
                v = emb_occ[oo[r] * 32 + lane];
            } else {
                const int d = lane - 32;
                float s = 0.f;
                #pragma unroll
                for (int t = 0; t < 6; ++t) s += mk[t] * emb_genre[gid[t] * 32 + d];
                v = s * inv_den;
            }
            lds_di[wid][r][128 + lane] = v;
            pe_sum += v; pe_sq += v * v;
        }
        if (lane < 8) lds_di[wid][r][192 + lane] = dense[(size_t)row * 8 + lane];

        float s2 = pe_sum + __shfl_xor(pe_sum, 32);
        float ss = pe_sq  + __shfl_xor(pe_sq, 32);
        float t2 = 0.5f * (s2 * s2 - ss);
        #pragma unroll
        for (int off = 16; off >= 1; off >>= 1) t2 += __shfl_xor(t2, off);

        float fo = fo_user[uid[r]] + fo_item[iid[r]] + fo_gender[gg[r]]
                 + fo_age[aa[r]] + fo_occ[oo[r]];
        float fg = 0.f;
        #pragma unroll
        for (int t = 0; t < 6; ++t) fg += mk[t] * fo_genre[gid[t]];
        fo += fg * inv_den;
        float dd = 0.f;
        #pragma unroll
        for (int j = 0; j < 8; ++j) dd += dense[(size_t)row * 8 + j] * dense_W[j];
        fo += dd + dense_b[0];

        if (lane == 0) lds_rs[wid][r] = fo + t2;
    }
    __syncthreads();

    // ---------------- Phase B: h1 = relu(deep_in @ W1^T + b1) ----------------
    // lane owns neurons j0=2*lane, j1=2*lane+1; coalesced packed weight loads.
    float acc0[ROWS_PER_WAVE], acc1[ROWS_PER_WAVE];
    #pragma unroll
    for (int r = 0; r < ROWS_PER_WAVE; ++r) { acc0[r] = 0.f; acc1[r] = 0.f; }

    const float4* __restrict__ div_ = reinterpret_cast<const float4*>(&lds_di[wid][0][0]); // row stride 50

    for (int k4 = 0; k4 < 50; ++k4) {
        const float4 w0 = W1p[(2 * k4) * 64 + lane];      // {j0k0,j1k0,j0k1,j1k1}
        const float4 w1 = W1p[(2 * k4 + 1) * 64 + lane];  // {j0k2,j1k2,j0k3,j1k3}
        #pragma unroll
        for (int r = 0; r < ROWS_PER_WAVE; ++r) {
            const float4 a = div_[r * 50 + k4];           // broadcast, conflict-free
            acc0[r] += w0.x * a.x + w0.z * a.y + w1.x * a.z + w1.z * a.w;
            acc1[r] += w0.y * a.x + w0.w * a.y + w1.y * a.z + w1.w * a.w;
        }
    }

    __syncthreads();  // deep_in reads done; overlay h1
    float* __restrict__ h1b = &lds_di[wid][0][0];  // h1[r][j] at r*128+j
    {
        const float2 bb = *reinterpret_cast<const float2*>(b1 + 2 * lane);
        #pragma unroll
        for (int r = 0; r < ROWS_PER_WAVE; ++r) {
            reinterpret_cast<float2*>(h1b)[r * 64 + lane] =
                make_float2(fmaxf(acc0[r] + bb.x, 0.f), fmaxf(acc1[r] + bb.y, 0.f));
        }
    }
    __syncthreads();

    // ---------------- Phase C: h2 = relu(h1 @ W2^T + b2), lane owns neuron lane ----
    float acc2[ROWS_PER_WAVE];
    #pragma unroll
    for (int r = 0; r < ROWS_PER_WAVE; ++r) acc2[r] = 0.f;

    const float4* __restrict__ h1v = reinterpret_cast<const float4*>(h1b); // row stride 32

    for (int k4 = 0; k4 < 32; ++k4) {
        const float4 w = W2p[k4 * 64 + lane];             // coalesced
        #pragma unroll
        for (int r = 0; r < ROWS_PER_WAVE; ++r) {
            const float4 h = h1v[r * 32 + k4];            // broadcast
            acc2[r] += w.x * h.x + w.y * h.y + w.z * h.z + w.w * h.w;
        }
    }

    // ---------------- Phase D: out = Wout.h2 + bout + first + second ----------------
    const float wo = Wout[lane];
    const float bb2 = b2[lane];
    const float bo = bout[0];
    for (int r = 0; r < ROWS_PER_WAVE; ++r) {
        const int row = rowBase + r;
        const float h2 = fmaxf(acc2[r] + bb2, 0.f);
        float v = wo * h2;
        #pragma unroll
        for (int off = 32; off >= 1; off >>= 1) v += __shfl_xor(v, off);
        if (lane == 0 && row < B) out[row] = v + bo + lds_rs[wid][r];
    }
}

extern "C" void kernel_launch(void* const* d_in, const int* in_sizes, int n_in,
                              void* d_out, int out_size, void* d_ws, size_t ws_size,
                              hipStream_t stream) {
    const int B = in_sizes[0];

    float4* W1p = reinterpret_cast<float4*>(d_ws);                  // 6400 float4 = 100 KB
    float4* W2p = reinterpret_cast<float4*>((char*)d_ws + 102400);  // 2048 float4 = 32 KB

    pack_weights<<<25, 256, 0, stream>>>(
        (const float*)d_in[22], (const float*)d_in[24], W1p, W2p);

    const int grid = (B + ROWS_PER_BLOCK - 1) / ROWS_PER_BLOCK;  // 512 at B=16384
    deepfm_kernel<<<grid, 256, 0, stream>>>(
        (const int*)d_in[0],  (const int*)d_in[1],  (const int*)d_in[2],
        (const int*)d_in[3],  (const int*)d_in[4],  (const int*)d_in[5],
        (const float*)d_in[6],  (const float*)d_in[7],
        (const float*)d_in[8],  (const float*)d_in[9],  (const float*)d_in[10],
        (const float*)d_in[11], (const float*)d_in[12], (const float*)d_in[13],
        (const float*)d_in[14], (const float*)d_in[15], (const float*)d_in[16],
        (const float*)d_in[17], (const float*)d_in[18], (const float*)d_in[19],
        (const float*)d_in[20], (const float*)d_in[21],
        W1p, (const float*)d_in[23],
        W2p, (const float*)d_in[25],
        (const float*)d_in[26], (const float*)d_in[27],
        (float*)d_out, B);
}